// Round 1
// baseline (32.870 us; speedup 1.0000x reference)
//
#include <hip/hip_runtime.h>
#include <hip/hip_bf16.h>

#define H_MODEL 1024
#define N_STATE 32
#define L_LEN   2048
#define BLK     256
#define LBLKS   (L_LEN / BLK)   // 8 blocks per channel

__global__ __launch_bounds__(BLK) void s4d_kernel(
    const float* __restrict__ log_dt,       // (H)
    const float* __restrict__ log_A_real,   // (H,N)
    const float* __restrict__ A_imag,       // (H,N)
    const float* __restrict__ B_re,         // (H,N)
    const float* __restrict__ B_im,         // (H,N)
    const float* __restrict__ C_re,         // (H,N)
    const float* __restrict__ C_im,         // (H,N)
    float* __restrict__ out)                // (H,L)
{
    const int bid  = blockIdx.x;
    const int h    = bid >> 3;          // bid / LBLKS
    const int lblk = bid & (LBLKS - 1);
    const int l    = lblk * BLK + threadIdx.x;

    __shared__ float s_dre[N_STATE];   // Re(dtA)
    __shared__ float s_dim[N_STATE];   // Im(dtA)
    __shared__ float s_wre[N_STATE];   // Re(C * B_bar)
    __shared__ float s_wim[N_STATE];   // Im(C * B_bar)

    if (threadIdx.x < N_STATE) {
        const int n   = threadIdx.x;
        const int idx = h * N_STATE + n;
        const float dt   = __expf(log_dt[h]);
        const float a_re = -__expf(log_A_real[idx]);
        const float a_im = A_imag[idx];
        const float dre  = a_re * dt;
        const float dim  = a_im * dt;

        // A_bar = exp(dtA)
        const float er = __expf(dre);
        float sn, cs;
        __sincosf(dim, &sn, &cs);
        const float abar_re = er * cs;
        const float abar_im = er * sn;

        // q = (A_bar - 1) / A   (complex divide via conj)
        const float num_re = abar_re - 1.0f;
        const float num_im = abar_im;
        const float inv_d  = 1.0f / (a_re * a_re + a_im * a_im);
        const float q_re   = (num_re * a_re + num_im * a_im) * inv_d;
        const float q_im   = (num_im * a_re - num_re * a_im) * inv_d;

        // B_bar = q * B
        const float br = B_re[idx], bi = B_im[idx];
        const float bb_re = q_re * br - q_im * bi;
        const float bb_im = q_re * bi + q_im * br;

        // w = C * B_bar
        const float cr = C_re[idx], ci = C_im[idx];
        s_wre[n] = cr * bb_re - ci * bb_im;
        s_wim[n] = cr * bb_im + ci * bb_re;
        s_dre[n] = dre;
        s_dim[n] = dim;
    }
    __syncthreads();

    const float t = (float)l;
    float acc = 0.0f;
    #pragma unroll
    for (int n = 0; n < N_STATE; ++n) {
        const float er = __expf(s_dre[n] * t);
        float sn, cs;
        __sincosf(s_dim[n] * t, &sn, &cs);
        acc += er * (s_wre[n] * cs - s_wim[n] * sn);
    }
    out[h * L_LEN + l] = acc;
}

extern "C" void kernel_launch(void* const* d_in, const int* in_sizes, int n_in,
                              void* d_out, int out_size, void* d_ws, size_t ws_size,
                              hipStream_t stream) {
    const float* log_dt     = (const float*)d_in[0];
    const float* log_A_real = (const float*)d_in[1];
    const float* A_imag     = (const float*)d_in[2];
    const float* B_re       = (const float*)d_in[3];
    const float* B_im       = (const float*)d_in[4];
    const float* C_re       = (const float*)d_in[5];
    const float* C_im       = (const float*)d_in[6];
    float* out              = (float*)d_out;

    dim3 grid(H_MODEL * LBLKS);
    dim3 block(BLK);
    s4d_kernel<<<grid, block, 0, stream>>>(log_dt, log_A_real, A_imag,
                                           B_re, B_im, C_re, C_im, out);
}

// Round 2
// 22.153 us; speedup vs baseline: 1.4838x; 1.4838x over previous
//
#include <hip/hip_runtime.h>
#include <hip/hip_bf16.h>

#define H_MODEL 1024
#define N_STATE 32
#define L_LEN   2048
#define BLK     256
#define GSTEP   8            // l-values per thread; BLK*GSTEP == L_LEN

__global__ __launch_bounds__(BLK) void s4d_kernel(
    const float* __restrict__ log_dt,       // (H)
    const float* __restrict__ log_A_real,   // (H,N)
    const float* __restrict__ A_imag,       // (H,N)
    const float* __restrict__ B_re,         // (H,N)
    const float* __restrict__ B_im,         // (H,N)
    const float* __restrict__ C_re,         // (H,N)
    const float* __restrict__ C_im,         // (H,N)
    float* __restrict__ out)                // (H,L)
{
    const int h = blockIdx.x;               // one block per channel

    __shared__ float s_dre[N_STATE], s_dim[N_STATE];   // dtA
    __shared__ float s_wre[N_STATE], s_wim[N_STATE];   // C*B_bar
    __shared__ float s_Er[N_STATE],  s_Ei[N_STATE];    // exp(dtA*BLK)

    if (threadIdx.x < N_STATE) {
        const int n   = threadIdx.x;
        const int idx = h * N_STATE + n;
        const float dt   = __expf(log_dt[h]);
        const float a_re = -__expf(log_A_real[idx]);
        const float a_im = A_imag[idx];
        const float dre  = a_re * dt;
        const float dim  = a_im * dt;

        // A_bar = exp(dtA)
        const float er = __expf(dre);
        float sn, cs;
        __sincosf(dim, &sn, &cs);
        const float abar_re = er * cs;
        const float abar_im = er * sn;

        // q = (A_bar - 1) / A
        const float num_re = abar_re - 1.0f;
        const float num_im = abar_im;
        const float inv_d  = 1.0f / (a_re * a_re + a_im * a_im);
        const float q_re   = (num_re * a_re + num_im * a_im) * inv_d;
        const float q_im   = (num_im * a_re - num_re * a_im) * inv_d;

        // B_bar = q * B ; w = C * B_bar
        const float br = B_re[idx], bi = B_im[idx];
        const float bb_re = q_re * br - q_im * bi;
        const float bb_im = q_re * bi + q_im * br;
        const float cr = C_re[idx], ci = C_im[idx];
        s_wre[n] = cr * bb_re - ci * bb_im;
        s_wim[n] = cr * bb_im + ci * bb_re;
        s_dre[n] = dre;
        s_dim[n] = dim;

        // step multiplier E = exp(dtA * BLK)
        const float erB = __expf(dre * (float)BLK);
        float snB, csB;
        __sincosf(dim * (float)BLK, &snB, &csB);
        s_Er[n] = erB * csB;
        s_Ei[n] = erB * snB;
    }
    __syncthreads();

    const float tt = (float)threadIdx.x;
    float acc[GSTEP];
    #pragma unroll
    for (int k = 0; k < GSTEP; ++k) acc[k] = 0.0f;

    #pragma unroll 4
    for (int n = 0; n < N_STATE; ++n) {
        const float dre = s_dre[n], dim = s_dim[n];
        const float wre = s_wre[n], wim = s_wim[n];
        const float Er  = s_Er[n],  Ei  = s_Ei[n];

        // z = w * exp(dtA * tid)   (transcendentals once per (n, thread))
        const float er = __expf(dre * tt);
        float sn, cs;
        __sincosf(dim * tt, &sn, &cs);
        float zr = er * (wre * cs - wim * sn);
        float zi = er * (wim * cs + wre * sn);

        #pragma unroll
        for (int k = 0; k < GSTEP; ++k) {
            acc[k] += zr;
            const float nzr = zr * Er - zi * Ei;
            const float nzi = zr * Ei + zi * Er;
            zr = nzr; zi = nzi;
        }
    }

    float* orow = out + h * L_LEN + threadIdx.x;
    #pragma unroll
    for (int k = 0; k < GSTEP; ++k)
        orow[k * BLK] = acc[k];
}

extern "C" void kernel_launch(void* const* d_in, const int* in_sizes, int n_in,
                              void* d_out, int out_size, void* d_ws, size_t ws_size,
                              hipStream_t stream) {
    const float* log_dt     = (const float*)d_in[0];
    const float* log_A_real = (const float*)d_in[1];
    const float* A_imag     = (const float*)d_in[2];
    const float* B_re       = (const float*)d_in[3];
    const float* B_im       = (const float*)d_in[4];
    const float* C_re       = (const float*)d_in[5];
    const float* C_im       = (const float*)d_in[6];
    float* out              = (float*)d_out;

    s4d_kernel<<<dim3(H_MODEL), dim3(BLK), 0, stream>>>(
        log_dt, log_A_real, A_imag, B_re, B_im, C_re, C_im, out);
}

// Round 3
// 15.391 us; speedup vs baseline: 2.1357x; 1.4393x over previous
//
#include <hip/hip_runtime.h>
#include <hip/hip_bf16.h>

#define H_MODEL 1024
#define N_STATE 32
#define L_LEN   2048
#define BLK     512          // one block per channel h; two n-halves
#define HALF    256
#define GSTEP   8            // l-values per thread (HALF * GSTEP == L_LEN)

__global__ __launch_bounds__(BLK, 8) void s4d_kernel(
    const float* __restrict__ log_dt,       // (H)
    const float* __restrict__ log_A_real,   // (H,N)
    const float* __restrict__ A_imag,       // (H,N)
    const float* __restrict__ B_re,         // (H,N)
    const float* __restrict__ B_im,         // (H,N)
    const float* __restrict__ C_re,         // (H,N)
    const float* __restrict__ C_im,         // (H,N)
    float* __restrict__ out)                // (H,L)
{
    const int h = blockIdx.x;

    __shared__ float4 s_c1[N_STATE];            // {dre, dim, wre, wim}
    __shared__ float4 s_c2[N_STATE];            // {Er, Ei, a=2Er, b=-|E|^2}
    __shared__ float  s_part[HALF][GSTEP + 1];  // pad 9 -> conflict-free

    if (threadIdx.x < N_STATE) {
        const int n   = threadIdx.x;
        const int idx = h * N_STATE + n;
        const float dt   = __expf(log_dt[h]);
        const float a_re = -__expf(log_A_real[idx]);
        const float a_im = A_imag[idx];
        const float dre  = a_re * dt;
        const float dim  = a_im * dt;

        // A_bar = exp(dtA)
        const float er = __expf(dre);
        float sn, cs;
        __sincosf(dim, &sn, &cs);
        const float abar_re = er * cs;
        const float abar_im = er * sn;

        // q = (A_bar - 1) / A
        const float num_re = abar_re - 1.0f;
        const float num_im = abar_im;
        const float inv_d  = 1.0f / (a_re * a_re + a_im * a_im);
        const float q_re   = (num_re * a_re + num_im * a_im) * inv_d;
        const float q_im   = (num_im * a_re - num_re * a_im) * inv_d;

        // B_bar = q * B ; w = C * B_bar
        const float br = B_re[idx], bi = B_im[idx];
        const float bb_re = q_re * br - q_im * bi;
        const float bb_im = q_re * bi + q_im * br;
        const float cr = C_re[idx], ci = C_im[idx];
        const float wre = cr * bb_re - ci * bb_im;
        const float wim = cr * bb_im + ci * bb_re;

        // E = exp(dtA * HALF); second-order recurrence coeffs
        const float erB = __expf(dre * (float)HALF);
        float snB, csB;
        __sincosf(dim * (float)HALF, &snB, &csB);
        const float Er = erB * csB;
        const float Ei = erB * snB;
        s_c1[n] = make_float4(dre, dim, wre, wim);
        s_c2[n] = make_float4(Er, Ei, 2.0f * Er, -(Er * Er + Ei * Ei));
    }
    __syncthreads();

    const int  hl    = threadIdx.x >> 8;        // which n-half
    const int  l     = threadIdx.x & (HALF - 1);
    const int  nbase = hl << 4;                 // 0 or 16
    const float t    = (float)l;

    float acc[GSTEP];
    #pragma unroll
    for (int k = 0; k < GSTEP; ++k) acc[k] = 0.0f;

    #pragma unroll 2
    for (int j = 0; j < N_STATE / 2; ++j) {
        const float4 c1 = s_c1[nbase + j];
        const float4 c2 = s_c2[nbase + j];

        // z0 = w * exp(dtA * l)
        const float er = __expf(c1.x * t);
        float sn, cs;
        __sincosf(c1.y * t, &sn, &cs);
        const float z0r = er * (c1.z * cs - c1.w * sn);
        const float z0i = er * (c1.w * cs + c1.z * sn);

        // r0 = Re(z0); r1 = Re(z0 * E)
        float rp = z0r;
        float rc = z0r * c2.x - z0i * c2.y;
        acc[0] += rp;
        acc[1] += rc;

        // r_k = a*r_{k-1} + b*r_{k-2}
        #pragma unroll
        for (int k = 2; k < GSTEP; ++k) {
            const float rn = __builtin_fmaf(c2.z, rc, c2.w * rp);
            acc[k] += rn;
            rp = rc; rc = rn;
        }
    }

    // combine the two n-halves: half 1 deposits, half 0 adds + stores
    if (hl == 1) {
        #pragma unroll
        for (int k = 0; k < GSTEP; ++k) s_part[l][k] = acc[k];
    }
    __syncthreads();
    if (hl == 0) {
        float* orow = out + h * L_LEN + l;
        #pragma unroll
        for (int k = 0; k < GSTEP; ++k)
            orow[k * HALF] = acc[k] + s_part[l][k];
    }
}

extern "C" void kernel_launch(void* const* d_in, const int* in_sizes, int n_in,
                              void* d_out, int out_size, void* d_ws, size_t ws_size,
                              hipStream_t stream) {
    const float* log_dt     = (const float*)d_in[0];
    const float* log_A_real = (const float*)d_in[1];
    const float* A_imag     = (const float*)d_in[2];
    const float* B_re       = (const float*)d_in[3];
    const float* B_im       = (const float*)d_in[4];
    const float* C_re       = (const float*)d_in[5];
    const float* C_im       = (const float*)d_in[6];
    float* out              = (float*)d_out;

    s4d_kernel<<<dim3(H_MODEL), dim3(BLK), 0, stream>>>(
        log_dt, log_A_real, A_imag, B_re, B_im, C_re, C_im, out);
}

// Round 4
// 13.505 us; speedup vs baseline: 2.4339x; 1.1397x over previous
//
#include <hip/hip_runtime.h>
#include <hip/hip_bf16.h>

#define H_MODEL 1024
#define N_STATE 32
#define L_LEN   2048
#define BLK     512
#define QL      128            // l-slots per block
#define GSTEP   16             // outputs per l-slot (QL * GSTEP == L_LEN)
#define NPQ     (N_STATE / 4)  // 8 n's per thread-quarter
#define NPAIR   (GSTEP / 2)

typedef float v2f __attribute__((ext_vector_type(2)));

__global__ __launch_bounds__(BLK, 8) void s4d_kernel(
    const float* __restrict__ log_dt,       // (H)
    const float* __restrict__ log_A_real,   // (H,N)
    const float* __restrict__ A_imag,       // (H,N)
    const float* __restrict__ B_re,         // (H,N)
    const float* __restrict__ B_im,         // (H,N)
    const float* __restrict__ C_re,         // (H,N)
    const float* __restrict__ C_im,         // (H,N)
    float* __restrict__ out)                // (H,L)
{
    const int h = blockIdx.x;

    __shared__ float4 s_c1[N_STATE];             // {dre, dim, wre, wim}
    __shared__ float4 s_c2[N_STATE];             // {Er, Ei, a=2Er, b=-|E|^2}
    __shared__ float  s_part[3][QL][GSTEP + 1];  // odd pad -> 2-way max (free)

    if (threadIdx.x < N_STATE) {
        const int n   = threadIdx.x;
        const int idx = h * N_STATE + n;
        const float dt   = __expf(log_dt[h]);
        const float a_re = -__expf(log_A_real[idx]);
        const float a_im = A_imag[idx];
        const float dre  = a_re * dt;
        const float dim  = a_im * dt;

        // A_bar = exp(dtA)
        const float er = __expf(dre);
        float sn, cs;
        __sincosf(dim, &sn, &cs);
        const float abar_re = er * cs;
        const float abar_im = er * sn;

        // q = (A_bar - 1) / A
        const float num_re = abar_re - 1.0f;
        const float num_im = abar_im;
        const float inv_d  = 1.0f / (a_re * a_re + a_im * a_im);
        const float q_re   = (num_re * a_re + num_im * a_im) * inv_d;
        const float q_im   = (num_im * a_re - num_re * a_im) * inv_d;

        // B_bar = q * B ; w = C * B_bar
        const float br = B_re[idx], bi = B_im[idx];
        const float bb_re = q_re * br - q_im * bi;
        const float bb_im = q_re * bi + q_im * br;
        const float cr = C_re[idx], ci = C_im[idx];
        const float wre = cr * bb_re - ci * bb_im;
        const float wim = cr * bb_im + ci * bb_re;

        // E = exp(dtA * QL); first-order-in-pairs coeffs
        const float erB = __expf(dre * (float)QL);
        float snB, csB;
        __sincosf(dim * (float)QL, &snB, &csB);
        const float Er = erB * csB;
        const float Ei = erB * snB;
        s_c1[n] = make_float4(dre, dim, wre, wim);
        s_c2[n] = make_float4(Er, Ei, 2.0f * Er, -(Er * Er + Ei * Ei));
    }
    __syncthreads();

    const int   q  = threadIdx.x >> 7;        // n-quarter 0..3
    const int   l  = threadIdx.x & (QL - 1);  // l-slot 0..127
    const int   nb = q * NPQ;
    const float t  = (float)l;

    v2f acc[NPAIR];
    #pragma unroll
    for (int j = 0; j < NPAIR; ++j) acc[j] = (v2f){0.0f, 0.0f};

    #pragma unroll 2
    for (int jn = 0; jn < NPQ; ++jn) {
        const float4 c1 = s_c1[nb + jn];
        const float4 c2 = s_c2[nb + jn];

        // derived stride-2 coeffs: a2 = a^2 + 2b = 2Re(E^2), b2 = -b^2 = -|E^2|^2
        const float a2 = __builtin_fmaf(c2.z, c2.z, c2.w + c2.w);
        const float b2 = -(c2.w * c2.w);
        const v2f A2 = {a2, a2};
        const v2f B2 = {b2, b2};

        // z0 = w * exp(dtA * l)
        const float er = __expf(c1.x * t);
        float sn, cs;
        __sincosf(c1.y * t, &sn, &cs);
        const float z0r = er * (c1.z * cs - c1.w * sn);
        const float z0i = er * (c1.w * cs + c1.z * sn);

        // r0..r3 scalar, then pair recurrence P_k = a2*P_{k-1} + b2*P_{k-2}
        const float r0 = z0r;
        const float r1 = z0r * c2.x - z0i * c2.y;
        const float r2 = __builtin_fmaf(c2.z, r1, c2.w * r0);
        const float r3 = __builtin_fmaf(c2.z, r2, c2.w * r1);

        v2f P0 = {r0, r1};
        v2f P1 = {r2, r3};
        acc[0] += P0;
        acc[1] += P1;
        #pragma unroll
        for (int k = 2; k < NPAIR; ++k) {
            const v2f Pn = __builtin_elementwise_fma(A2, P1, B2 * P0);
            acc[k] += Pn;
            P0 = P1; P1 = Pn;
        }
    }

    // combine the four n-quarters: q1..q3 deposit, q0 sums + stores
    if (q != 0) {
        #pragma unroll
        for (int j = 0; j < NPAIR; ++j) {
            s_part[q - 1][l][2 * j]     = acc[j].x;
            s_part[q - 1][l][2 * j + 1] = acc[j].y;
        }
    }
    __syncthreads();
    if (q == 0) {
        #pragma unroll
        for (int b = 0; b < 3; ++b) {
            #pragma unroll
            for (int j = 0; j < NPAIR; ++j) {
                acc[j].x += s_part[b][l][2 * j];
                acc[j].y += s_part[b][l][2 * j + 1];
            }
        }
        float* orow = out + h * L_LEN + l;
        #pragma unroll
        for (int j = 0; j < NPAIR; ++j) {
            orow[(2 * j) * QL]     = acc[j].x;
            orow[(2 * j + 1) * QL] = acc[j].y;
        }
    }
}

extern "C" void kernel_launch(void* const* d_in, const int* in_sizes, int n_in,
                              void* d_out, int out_size, void* d_ws, size_t ws_size,
                              hipStream_t stream) {
    const float* log_dt     = (const float*)d_in[0];
    const float* log_A_real = (const float*)d_in[1];
    const float* A_imag     = (const float*)d_in[2];
    const float* B_re       = (const float*)d_in[3];
    const float* B_im       = (const float*)d_in[4];
    const float* C_re       = (const float*)d_in[5];
    const float* C_im       = (const float*)d_in[6];
    float* out              = (float*)d_out;

    s4d_kernel<<<dim3(H_MODEL), dim3(BLK), 0, stream>>>(
        log_dt, log_A_real, A_imag, B_re, B_im, C_re, C_im, out);
}

// Round 5
// 13.070 us; speedup vs baseline: 2.5149x; 1.0333x over previous
//
#include <hip/hip_runtime.h>
#include <hip/hip_bf16.h>

#define H_MODEL 1024
#define N_STATE 32
#define L_LEN   2048
#define BLK     512
#define QL      128            // l-slots per block
#define GSTEP   16             // outputs per l-slot (QL * GSTEP == L_LEN)
#define NPQ     (N_STATE / 4)  // 8 n's per thread-quarter
#define NPAIR   (GSTEP / 2)

typedef float v2f __attribute__((ext_vector_type(2)));

__device__ __forceinline__ float vsin_rev(float x) {  // sin(2*pi*x)
    float r; asm("v_sin_f32 %0, %1" : "=v"(r) : "v"(x)); return r;
}
__device__ __forceinline__ float vcos_rev(float x) {  // cos(2*pi*x)
    float r; asm("v_cos_f32 %0, %1" : "=v"(r) : "v"(x)); return r;
}

__global__ __launch_bounds__(BLK, 8) void s4d_kernel(
    const float* __restrict__ log_dt,       // (H)
    const float* __restrict__ log_A_real,   // (H,N)
    const float* __restrict__ A_imag,       // (H,N)
    const float* __restrict__ B_re,         // (H,N)
    const float* __restrict__ B_im,         // (H,N)
    const float* __restrict__ C_re,         // (H,N)
    const float* __restrict__ C_im,         // (H,N)
    float* __restrict__ out)                // (H,L)
{
    const int h = blockIdx.x;

    __shared__ float4 s_c1[N_STATE];             // {dre*log2e, dim/2pi, wre, wim}
    __shared__ float4 s_c2[N_STATE];             // {Er, Ei, a=2Er, b=-|E|^2}
    __shared__ float  s_part[4][QL][GSTEP + 1];  // odd pad: conflict-free

    if (threadIdx.x < N_STATE) {
        const int n   = threadIdx.x;
        const int idx = h * N_STATE + n;
        const float dt   = __expf(log_dt[h]);
        const float a_re = -__expf(log_A_real[idx]);
        const float a_im = A_imag[idx];
        const float dre  = a_re * dt;
        const float dim  = a_im * dt;

        // A_bar = exp(dtA)
        const float er = __expf(dre);
        float sn, cs;
        __sincosf(dim, &sn, &cs);
        const float abar_re = er * cs;
        const float abar_im = er * sn;

        // q = (A_bar - 1) / A
        const float num_re = abar_re - 1.0f;
        const float num_im = abar_im;
        const float inv_d  = 1.0f / (a_re * a_re + a_im * a_im);
        const float q_re   = (num_re * a_re + num_im * a_im) * inv_d;
        const float q_im   = (num_im * a_re - num_re * a_im) * inv_d;

        // B_bar = q * B ; w = C * B_bar
        const float br = B_re[idx], bi = B_im[idx];
        const float bb_re = q_re * br - q_im * bi;
        const float bb_im = q_re * bi + q_im * br;
        const float cr = C_re[idx], ci = C_im[idx];
        const float wre = cr * bb_re - ci * bb_im;
        const float wim = cr * bb_im + ci * bb_re;

        // E = exp(dtA * QL); pair-recurrence coeffs
        const float erB = __expf(dre * (float)QL);
        float snB, csB;
        __sincosf(dim * (float)QL, &snB, &csB);
        const float Er = erB * csB;
        const float Ei = erB * snB;
        // fold log2(e) and 1/(2pi) into the per-t transcendental args
        s_c1[n] = make_float4(dre * 1.44269504088896341f,
                              dim * 0.15915494309189535f, wre, wim);
        s_c2[n] = make_float4(Er, Ei, 2.0f * Er, -(Er * Er + Ei * Ei));
    }
    __syncthreads();

    const int   q  = threadIdx.x >> 7;        // n-quarter 0..3
    const int   l  = threadIdx.x & (QL - 1);  // l-slot 0..127
    const int   nb = q * NPQ;
    const float t  = (float)l;

    v2f acc[NPAIR];
    #pragma unroll
    for (int j = 0; j < NPAIR; ++j) acc[j] = (v2f){0.0f, 0.0f};

    #pragma unroll 2
    for (int jn = 0; jn < NPQ; ++jn) {
        const float4 c1 = s_c1[nb + jn];
        const float4 c2 = s_c2[nb + jn];

        // stride-2 coeffs: a2 = a^2 + 2b, b2 = -b^2
        const float a2 = __builtin_fmaf(c2.z, c2.z, c2.w + c2.w);
        const float b2 = -(c2.w * c2.w);
        const v2f A2 = {a2, a2};
        const v2f B2 = {b2, b2};

        // z0 = w * exp(dtA * l) via hw trans: exp2 + sin/cos in revolutions
        const float er = __builtin_amdgcn_exp2f(c1.x * t);
        const float uf = __builtin_amdgcn_fractf(c1.y * t);
        const float sn = vsin_rev(uf);
        const float cs = vcos_rev(uf);
        const float z0r = er * __builtin_fmaf(c1.z, cs, -(c1.w * sn));
        const float z0i = er * __builtin_fmaf(c1.w, cs,  (c1.z * sn));

        // heads r0..r3, then pair recurrence P_k = a2*P_{k-1} + b2*P_{k-2}
        const float r0 = z0r;
        const float r1 = __builtin_fmaf(z0r, c2.x, -(z0i * c2.y));
        const float r2 = __builtin_fmaf(c2.z, r1, c2.w * r0);
        const float r3 = __builtin_fmaf(c2.z, r2, c2.w * r1);

        v2f P0 = {r0, r1};
        v2f P1 = {r2, r3};
        acc[0] += P0;
        acc[1] += P1;
        #pragma unroll
        for (int k = 2; k < NPAIR; ++k) {
            const v2f Pn = __builtin_elementwise_fma(A2, P1, B2 * P0);
            acc[k] += Pn;
            P0 = P1; P1 = Pn;
        }
    }

    // all quarters deposit; each quarter then sums + stores 4 of 16 outputs
    #pragma unroll
    for (int j = 0; j < NPAIR; ++j) {
        s_part[q][l][2 * j]     = acc[j].x;
        s_part[q][l][2 * j + 1] = acc[j].y;
    }
    __syncthreads();

    {
        const int k0 = q * (GSTEP / 4);
        float* orow = out + h * L_LEN + l;
        #pragma unroll
        for (int j = 0; j < GSTEP / 4; ++j) {
            const int k = k0 + j;
            const float s = (s_part[0][l][k] + s_part[1][l][k])
                          + (s_part[2][l][k] + s_part[3][l][k]);
            orow[k * QL] = s;
        }
    }
}

extern "C" void kernel_launch(void* const* d_in, const int* in_sizes, int n_in,
                              void* d_out, int out_size, void* d_ws, size_t ws_size,
                              hipStream_t stream) {
    const float* log_dt     = (const float*)d_in[0];
    const float* log_A_real = (const float*)d_in[1];
    const float* A_imag     = (const float*)d_in[2];
    const float* B_re       = (const float*)d_in[3];
    const float* B_im       = (const float*)d_in[4];
    const float* C_re       = (const float*)d_in[5];
    const float* C_im       = (const float*)d_in[6];
    float* out              = (float*)d_out;

    s4d_kernel<<<dim3(H_MODEL), dim3(BLK), 0, stream>>>(
        log_dt, log_A_real, A_imag, B_re, B_im, C_re, C_im, out);
}